// Round 12
// baseline (1211.636 us; speedup 1.0000x reference)
//
#include <hip/hip_runtime.h>
#include <hip/hip_bf16.h>
#include <math.h>
#include <stdint.h>

// ---------------------------------------------------------------------------
// Problem constants
// ---------------------------------------------------------------------------
#define IDIM   256
#define NU     512
#define NL     4
#define EU     2048
#define NH     8
#define DK     64
#define TT     1024
#define NB     8
#define MTOT   8192

typedef short  bf16x8 __attribute__((ext_vector_type(8)));
typedef float  f32x4  __attribute__((ext_vector_type(4)));
typedef unsigned short ushortv2 __attribute__((ext_vector_type(2)));

// fp32 -> bf16 bits, round-to-nearest-even
__device__ __forceinline__ unsigned short f2b(float x) {
  unsigned int u = __float_as_uint(x);
  u += 0x7fffu + ((u >> 16) & 1u);
  return (unsigned short)(u >> 16);
}

// async 16B global -> LDS (size must be literal 16)
__device__ __forceinline__ void gload16(const unsigned short* g, unsigned short* l) {
  auto gp = reinterpret_cast<const __attribute__((address_space(1))) unsigned int*>(
      reinterpret_cast<uintptr_t>(g));
  auto lp = reinterpret_cast<__attribute__((address_space(3))) unsigned int*>(
      reinterpret_cast<uintptr_t>(l));
  __builtin_amdgcn_global_load_lds(gp, lp, 16, 0, 0);
}

// ---------------------------------------------------------------------------
// fp32 -> bf16 bulk convert (8 elems/thread)
// ---------------------------------------------------------------------------
__global__ __launch_bounds__(256) void cvt_bf16(
    const float* __restrict__ src, unsigned short* __restrict__ dst, int n) {
  int i = (blockIdx.x * 256 + threadIdx.x) * 8;
  if (i >= n) return;
  float4 a = *(const float4*)(src + i);
  float4 b = *(const float4*)(src + i + 4);
  bf16x8 r;
  r[0] = (short)f2b(a.x); r[1] = (short)f2b(a.y);
  r[2] = (short)f2b(a.z); r[3] = (short)f2b(a.w);
  r[4] = (short)f2b(b.x); r[5] = (short)f2b(b.y);
  r[6] = (short)f2b(b.z); r[7] = (short)f2b(b.w);
  *(bf16x8*)(dst + i) = r;
}

// ---------------------------------------------------------------------------
// bf16 MFMA GEMM core, 2-phase double-buffered staging:
// BM=BN=128, BK=32, LDS 2x[128][32] per matrix (32KB total), 4 waves (2x2).
// Per K-step: issue next tile's 4 global_load_lds (async, vmcnt in flight),
// then ds_read+16 MFMA on current buffer, ONE __syncthreads (its vmcnt(0)
// drain lands after compute -> load latency overlaps MFMA phase).
// Staging map: (ii,wv) covers rows ii*64+wv*16 .. +16; lane l -> row +l/4,
// col shorts (l&3)*8 (16B/lane, LDS dest = uniform base + lane*16: linear).
// MODE: 0 = fp32 store, 1 = bf16 store, 2 = fp32 atomicAdd (split-K).
// ---------------------------------------------------------------------------
#define GEMM_STAGE(BUF, KK)                                                  \
  _Pragma("unroll") for (int ii = 0; ii < 2; ++ii) {                         \
    gload16(ag + (size_t)(ii * 64) * kdim + (KK), &As[BUF][ii * 2048 + wv * 512]); \
    gload16(bg + (size_t)(ii * 64) * kdim + (KK), &Bs[BUF][ii * 2048 + wv * 512]); \
  }

#define GEMM_CORE(K_, KBEG, KEND)                                            \
  __shared__ unsigned short As[2][128 * 32];                                 \
  __shared__ unsigned short Bs[2][128 * 32];                                 \
  const int kdim = (K_);                                                     \
  const int tid  = threadIdx.x;                                              \
  const int lane = tid & 63;                                                 \
  const int wv   = tid >> 6;                                                 \
  const int wm   = (wv >> 1) * 64;                                           \
  const int wn   = (wv & 1) * 64;                                            \
  const int fr   = lane & 15;                                                \
  const int fc   = lane >> 4;                                                \
  const int srow = wv * 16 + (lane >> 2);                                    \
  const int skk  = (lane & 3) * 8;                                           \
  const unsigned short* ag = A + (size_t)(m0 + srow) * kdim + skk;           \
  const unsigned short* bg = W + (size_t)(n0 + srow) * kdim + skk;           \
  f32x4 acc[4][4];                                                           \
  _Pragma("unroll") for (int i = 0; i < 4; ++i)                              \
    _Pragma("unroll") for (int j = 0; j < 4; ++j)                            \
      acc[i][j] = (f32x4){0.f, 0.f, 0.f, 0.f};                               \
  int cur = 0;                                                               \
  GEMM_STAGE(0, (KBEG))                                                      \
  for (int k0 = (KBEG); k0 < (KEND); k0 += 32) {                             \
    __syncthreads();  /* drains vmcnt: buf[cur] resident; prev reads done */ \
    if (k0 + 32 < (KEND)) { GEMM_STAGE(cur ^ 1, k0 + 32) }                   \
    const unsigned short* acu = As[cur];                                     \
    const unsigned short* bcu = Bs[cur];                                     \
    bf16x8 af[4], bfr[4];                                                    \
    _Pragma("unroll") for (int mi = 0; mi < 4; ++mi)                         \
      af[mi] = *(const bf16x8*)&acu[(wm + mi * 16 + fr) * 32 + fc * 8];      \
    _Pragma("unroll") for (int ni = 0; ni < 4; ++ni)                         \
      bfr[ni] = *(const bf16x8*)&bcu[(wn + ni * 16 + fr) * 32 + fc * 8];     \
    _Pragma("unroll") for (int mi = 0; mi < 4; ++mi)                         \
      _Pragma("unroll") for (int ni = 0; ni < 4; ++ni)                       \
        acc[mi][ni] = __builtin_amdgcn_mfma_f32_16x16x32_bf16(               \
            af[mi], bfr[ni], acc[mi][ni], 0, 0, 0);                          \
    cur ^= 1;                                                                \
  }

template<int MODE, bool RELU>
__global__ __launch_bounds__(256) void gemm_bf(
    const unsigned short* __restrict__ A, const unsigned short* __restrict__ W,
    const float* __restrict__ bias, float* __restrict__ Cf,
    unsigned short* __restrict__ Cb, int M, int N, int K, int kchunk) {
  const int m0 = blockIdx.y * 128;
  const int n0 = blockIdx.x * 128;
  const int kbeg = blockIdx.z * kchunk;
  const int kend = kbeg + kchunk;
  GEMM_CORE(K, kbeg, kend)

  const bool addb = (blockIdx.z == 0);
#pragma unroll
  for (int ni = 0; ni < 4; ++ni) {
    const int col = n0 + wn + ni * 16 + fr;
    const float bb = (MODE != 2 || addb) ? bias[col] : 0.f;
#pragma unroll
    for (int mi = 0; mi < 4; ++mi) {
      const int row = m0 + wm + mi * 16 + fc * 4;
#pragma unroll
      for (int j = 0; j < 4; ++j) {
        size_t off = (size_t)(row + j) * N + col;
        float r = acc[mi][ni][j] + bb;
        if (RELU) r = fmaxf(r, 0.f);
        if (MODE == 0) Cf[off] = r;
        else if (MODE == 1) Cb[off] = f2b(r);
        else atomicAdd(&Cf[off], r);
      }
    }
  }
}

// Fused QKV: blockIdx.z picks (W,bias,out); q gets the 1/sqrt(dk) scale.
__global__ __launch_bounds__(256) void gemm_qkv(
    const unsigned short* __restrict__ A,
    const unsigned short* __restrict__ Wq, const unsigned short* __restrict__ Wk,
    const unsigned short* __restrict__ Wv,
    const float* __restrict__ bq, const float* __restrict__ bk,
    const float* __restrict__ bv,
    unsigned short* __restrict__ Oq, unsigned short* __restrict__ Ok,
    unsigned short* __restrict__ Ov) {
  const int zz = blockIdx.z;
  const unsigned short* W  = zz == 0 ? Wq : (zz == 1 ? Wk : Wv);
  const float* bias        = zz == 0 ? bq : (zz == 1 ? bk : bv);
  unsigned short* C        = zz == 0 ? Oq : (zz == 1 ? Ok : Ov);
  const float scale        = zz == 0 ? 0.125f : 1.0f;
  const int m0 = blockIdx.y * 128;
  const int n0 = blockIdx.x * 128;
  GEMM_CORE(NU, 0, NU)

#pragma unroll
  for (int ni = 0; ni < 4; ++ni) {
    const int col = n0 + wn + ni * 16 + fr;
    const float bb = bias[col];
#pragma unroll
    for (int mi = 0; mi < 4; ++mi) {
      const int row = m0 + wm + mi * 16 + fc * 4;
#pragma unroll
      for (int j = 0; j < 4; ++j)
        C[(size_t)(row + j) * NU + col] = f2b((acc[mi][ni][j] + bb) * scale);
    }
  }
}

// ---------------------------------------------------------------------------
// In-place LayerNorm (fp32), optional bf16 copy for GEMM consumption.
// ---------------------------------------------------------------------------
template<bool WB>
__global__ __launch_bounds__(256) void layernorm_inplace(
    float* __restrict__ e, const float* __restrict__ g,
    const float* __restrict__ b, unsigned short* __restrict__ eb) {
  const int row = blockIdx.x;
  float* x = e + (size_t)row * NU;
  const int tid = threadIdx.x;

  float2 v = *(const float2*)&x[tid * 2];
  float sum = v.x + v.y;
  float sq  = v.x * v.x + v.y * v.y;
#pragma unroll
  for (int o = 32; o > 0; o >>= 1) {
    sum += __shfl_down(sum, o);
    sq  += __shfl_down(sq, o);
  }
  __shared__ float ps[4], pq[4], stat[2];
  const int wid = tid >> 6, lane = tid & 63;
  if (lane == 0) { ps[wid] = sum; pq[wid] = sq; }
  __syncthreads();
  if (tid == 0) {
    float s = ps[0] + ps[1] + ps[2] + ps[3];
    float q = pq[0] + pq[1] + pq[2] + pq[3];
    float mu = s * (1.0f / NU);
    float var = q * (1.0f / NU) - mu * mu;
    stat[0] = mu;
    stat[1] = rsqrtf(var + 1e-5f);
  }
  __syncthreads();
  const float mu = stat[0], rstd = stat[1];
  const float2 gg = *(const float2*)&g[tid * 2];
  const float2 bb = *(const float2*)&b[tid * 2];
  v.x = (v.x - mu) * rstd * gg.x + bb.x;
  v.y = (v.y - mu) * rstd * gg.y + bb.y;
  *(float2*)&x[tid * 2] = v;
  if (WB) {
    ushortv2 o = {f2b(v.x), f2b(v.y)};
    *(ushortv2*)&eb[(size_t)row * NU + tid * 2] = o;
  }
}

// ---------------------------------------------------------------------------
// MFMA flash attention, bf16 in / bf16 out (q pre-scaled by 1/8).
// Block = 4 waves x 16 q-rows; grid (16,8,8)=1024 blocks.
// Vt stride 66 (was 72): transpose writes ~4-way instead of 8-way conflicts.
// T13 defer-max: skip rescale pass unless any row max grew > 8.
// ---------------------------------------------------------------------------
__global__ __launch_bounds__(256) void flash_attn_mfma(
    const unsigned short* __restrict__ Q, const unsigned short* __restrict__ K,
    const unsigned short* __restrict__ V, unsigned short* __restrict__ O) {
  constexpr int LSTR = 72;
  constexpr int VSTR = 66;
  __shared__ unsigned short Ks[64 * LSTR];   // [k][d]
  __shared__ unsigned short Vt[64 * VSTR];   // [d][k]
  __shared__ unsigned short Ps[64 * LSTR];   // [q][k]

  const int b = blockIdx.z, h = blockIdx.y;
  const int q0 = blockIdx.x * 64;
  const int tid = threadIdx.x;
  const int lane = tid & 63;
  const int w = tid >> 6;
  const int fr = lane & 15;
  const int fc = lane >> 4;

  const size_t hb = ((size_t)b * TT) * NU + h * DK;

  bf16x8 qf[2];
#pragma unroll
  for (int kc = 0; kc < 2; ++kc)
    qf[kc] = *(const bf16x8*)(Q + hb +
        (size_t)(q0 + w * 16 + fr) * NU + kc * 32 + fc * 8);

  f32x4 ctx[4];
#pragma unroll
  for (int ni = 0; ni < 4; ++ni) ctx[ni] = (f32x4){0.f, 0.f, 0.f, 0.f};
  float m_run[4], l_run[4];
#pragma unroll
  for (int j = 0; j < 4; ++j) { m_run[j] = -1e30f; l_run[j] = 0.f; }

  const int sr = tid >> 2;
  const int sd = (tid & 3) * 16;

  for (int kt = 0; kt < TT; kt += 64) {
    const unsigned short* kp = K + hb + (size_t)(kt + sr) * NU + sd;
    const unsigned short* vp = V + hb + (size_t)(kt + sr) * NU + sd;
    bf16x8 k0 = *(const bf16x8*)kp, k1 = *(const bf16x8*)(kp + 8);
    bf16x8 v0 = *(const bf16x8*)vp, v1 = *(const bf16x8*)(vp + 8);

    __syncthreads();
    *(bf16x8*)&Ks[sr * LSTR + sd]     = k0;
    *(bf16x8*)&Ks[sr * LSTR + sd + 8] = k1;
#pragma unroll
    for (int t = 0; t < 8; ++t) {
      Vt[(sd + t)     * VSTR + sr] = (unsigned short)v0[t];
      Vt[(sd + t + 8) * VSTR + sr] = (unsigned short)v1[t];
    }
    __syncthreads();

    bf16x8 kf[4][2];
#pragma unroll
    for (int ni = 0; ni < 4; ++ni)
#pragma unroll
      for (int kc = 0; kc < 2; ++kc)
        kf[ni][kc] = *(const bf16x8*)&Ks[(ni * 16 + fr) * LSTR + kc * 32 + fc * 8];

    f32x4 sacc[4];
#pragma unroll
    for (int ni = 0; ni < 4; ++ni) sacc[ni] = (f32x4){0.f, 0.f, 0.f, 0.f};
#pragma unroll
    for (int kc = 0; kc < 2; ++kc)
#pragma unroll
      for (int ni = 0; ni < 4; ++ni)
        sacc[ni] = __builtin_amdgcn_mfma_f32_16x16x32_bf16(
            qf[kc], kf[ni][kc], sacc[ni], 0, 0, 0);

    // tile row max (C-layout: col across 16 lanes, row = fc*4+j)
    float cm[4];
#pragma unroll
    for (int j = 0; j < 4; ++j)
      cm[j] = fmaxf(fmaxf(sacc[0][j], sacc[1][j]),
                    fmaxf(sacc[2][j], sacc[3][j]));
#pragma unroll
    for (int mask = 1; mask < 16; mask <<= 1)
#pragma unroll
      for (int j = 0; j < 4; ++j)
        cm[j] = fmaxf(cm[j], __shfl_xor(cm[j], mask));

    // T13 defer-max: rescale only when some row max grew past threshold
    int need = (cm[0] > m_run[0] + 8.f) | (cm[1] > m_run[1] + 8.f) |
               (cm[2] > m_run[2] + 8.f) | (cm[3] > m_run[3] + 8.f);
    if (__any(need)) {
#pragma unroll
      for (int j = 0; j < 4; ++j) {
        float mn = fmaxf(m_run[j], cm[j]);
        float corr = __expf(m_run[j] - mn);
        m_run[j] = mn;
        l_run[j] *= corr;
#pragma unroll
        for (int ni = 0; ni < 4; ++ni) ctx[ni][j] *= corr;
      }
    }
#pragma unroll
    for (int j = 0; j < 4; ++j)
#pragma unroll
      for (int ni = 0; ni < 4; ++ni) {
        float p = __expf(sacc[ni][j] - m_run[j]);   // bounded by e^8
        l_run[j] += p;
        Ps[(w * 16 + fc * 4 + j) * LSTR + ni * 16 + fr] = f2b(p);
      }

    bf16x8 pf[2], vf[4][2];
#pragma unroll
    for (int kc = 0; kc < 2; ++kc)
      pf[kc] = *(const bf16x8*)&Ps[(w * 16 + fr) * LSTR + kc * 32 + fc * 8];
#pragma unroll
    for (int ni = 0; ni < 4; ++ni)
#pragma unroll
      for (int kc = 0; kc < 2; ++kc)
        vf[ni][kc] = *(const bf16x8*)&Vt[(ni * 16 + fr) * VSTR + kc * 32 + fc * 8];
#pragma unroll
    for (int kc = 0; kc < 2; ++kc)
#pragma unroll
      for (int ni = 0; ni < 4; ++ni)
        ctx[ni] = __builtin_amdgcn_mfma_f32_16x16x32_bf16(
            pf[kc], vf[ni][kc], ctx[ni], 0, 0, 0);
  }

#pragma unroll
  for (int j = 0; j < 4; ++j) {
    float l = l_run[j];
#pragma unroll
    for (int mask = 1; mask < 16; mask <<= 1)
      l += __shfl_xor(l, mask);
    const float inv = 1.0f / l;
    const int row = q0 + w * 16 + fc * 4 + j;
    unsigned short* dst = O + hb + (size_t)row * NU;
#pragma unroll
    for (int ni = 0; ni < 4; ++ni)
      dst[ni * 16 + fr] = f2b(ctx[ni][j] * inv);
  }
}

// ---------------------------------------------------------------------------
// Launcher.  ws (64MB) layout in bf16 units (1M = 1<<20 shorts):
//   [0,4M)q [4M,8M)k [8M,12M)v [12M,16M)ctx   --- hdn = [0,16M)
//   x_bf=[4M,6M) Win_bf=[6M,~) (dead before q/k/v written)
//   [16M,20M) e_bf
//   [20M,21M)Wq [21,22)Wk [22,23)Wv [23,24)Wo [24M,28M)W1 [28M,32M)W2
// ---------------------------------------------------------------------------
extern "C" void kernel_launch(void* const* d_in, const int* in_sizes, int n_in,
                              void* d_out, int out_size, void* d_ws, size_t ws_size,
                              hipStream_t stream) {
  const float* x     = (const float*)d_in[0];
  const float* Win   = (const float*)d_in[1];
  const float* bin_  = (const float*)d_in[2];
  const float* ln1_g = (const float*)d_in[3];
  const float* ln1_b = (const float*)d_in[4];
  const float* Wq    = (const float*)d_in[5];
  const float* bq    = (const float*)d_in[6];
  const float* Wk    = (const float*)d_in[7];
  const float* bk    = (const float*)d_in[8];
  const float* Wv    = (const float*)d_in[9];
  const float* bv    = (const float*)d_in[10];
  const float* Wo    = (const float*)d_in[11];
  const float* bo    = (const float*)d_in[12];
  const float* ln2_g = (const float*)d_in[13];
  const float* ln2_b = (const float*)d_in[14];
  const float* W1    = (const float*)d_in[15];
  const float* b1    = (const float*)d_in[16];
  const float* W2    = (const float*)d_in[17];
  const float* b2    = (const float*)d_in[18];
  const float* lno_g = (const float*)d_in[19];
  const float* lno_b = (const float*)d_in[20];

  float* e = (float*)d_out;
  unsigned short* wsb = (unsigned short*)d_ws;
  const size_t M1 = 1u << 20;
  unsigned short* q    = wsb;
  unsigned short* k    = wsb + 4 * M1;
  unsigned short* v    = wsb + 8 * M1;
  unsigned short* ctx  = wsb + 12 * M1;
  unsigned short* hdn  = wsb;                 // [0,16M)
  unsigned short* xbf  = wsb + 4 * M1;        // dead before k written
  unsigned short* winb = wsb + 6 * M1;
  unsigned short* ebf  = wsb + 16 * M1;
  unsigned short* wqb  = wsb + 20 * M1;
  unsigned short* wkb  = wsb + 21 * M1;
  unsigned short* wvb  = wsb + 22 * M1;
  unsigned short* wob  = wsb + 23 * M1;
  unsigned short* w1b  = wsb + 24 * M1;
  unsigned short* w2b  = wsb + 28 * M1;

  const dim3 blk(256);
  // one-time bf16 conversion of x + all weights
  cvt_bf16<<<1024, blk, 0, stream>>>(x,   xbf,  MTOT * IDIM);
  cvt_bf16<<<64,   blk, 0, stream>>>(Win, winb, NU * IDIM);
  cvt_bf16<<<512,  blk, 0, stream>>>(Wq,  wqb,  NL * NU * NU);
  cvt_bf16<<<512,  blk, 0, stream>>>(Wk,  wkb,  NL * NU * NU);
  cvt_bf16<<<512,  blk, 0, stream>>>(Wv,  wvb,  NL * NU * NU);
  cvt_bf16<<<512,  blk, 0, stream>>>(Wo,  wob,  NL * NU * NU);
  cvt_bf16<<<2048, blk, 0, stream>>>(W1,  w1b,  NL * EU * NU);
  cvt_bf16<<<2048, blk, 0, stream>>>(W2,  w2b,  NL * NU * EU);

  const dim3 gProjIn(NU / 128, MTOT / 128);      // 256 blocks
  const dim3 gQKV(NU / 128, MTOT / 128, 3);      // 768
  const dim3 gWo(NU / 128, MTOT / 128, 4);       // 1024, split-K 4
  const dim3 gF1(EU / 128, MTOT / 128);          // 1024
  const dim3 gF2(NU / 128, MTOT / 128, 4);       // 1024, split-K 4
  const dim3 gAttn(TT / 64, NH, NB);             // 1024

  // e = x @ Win^T + bin   (fp32 out)
  gemm_bf<0, false><<<gProjIn, blk, 0, stream>>>(
      xbf, winb, bin_, e, nullptr, MTOT, NU, IDIM, IDIM);

  for (int i = 0; i < NL; ++i) {
    // LN1 -> e (fp32) + ebf (bf16)
    layernorm_inplace<true><<<MTOT, blk, 0, stream>>>(e, ln1_g + i * NU, ln1_b + i * NU, ebf);

    // q,k,v = ebf @ W^T + b  (bf16 out; q scaled by 1/8)
    gemm_qkv<<<gQKV, blk, 0, stream>>>(ebf, wqb + (size_t)i * NU * NU,
                                       wkb + (size_t)i * NU * NU,
                                       wvb + (size_t)i * NU * NU,
                                       bq + i * NU, bk + i * NU, bv + i * NU,
                                       q, k, v);

    flash_attn_mfma<<<gAttn, blk, 0, stream>>>(q, k, v, ctx);

    // e += ctx @ Wo^T + bo   (split-K 4, atomic)
    gemm_bf<2, false><<<gWo, blk, 0, stream>>>(
        ctx, wob + (size_t)i * NU * NU, bo + i * NU, e, nullptr,
        MTOT, NU, NU, NU / 4);

    // LN2 -> e + ebf
    layernorm_inplace<true><<<MTOT, blk, 0, stream>>>(e, ln2_g + i * NU, ln2_b + i * NU, ebf);

    // hdn = relu(ebf @ W1^T + b1)  (bf16 out)
    gemm_bf<1, true><<<gF1, blk, 0, stream>>>(
        ebf, w1b + (size_t)i * EU * NU, b1 + i * EU, nullptr, hdn,
        MTOT, EU, NU, NU);

    // e += hdn @ W2^T + b2   (split-K 4, atomic)
    gemm_bf<2, false><<<gF2, blk, 0, stream>>>(
        hdn, w2b + (size_t)i * NU * EU, b2 + i * NU, e, nullptr,
        MTOT, NU, EU, EU / 4);
  }

  layernorm_inplace<false><<<MTOT, blk, 0, stream>>>(e, lno_g, lno_b, nullptr);
}

// Round 13
// 1110.379 us; speedup vs baseline: 1.0912x; 1.0912x over previous
//
#include <hip/hip_runtime.h>
#include <hip/hip_bf16.h>
#include <math.h>
#include <stdint.h>

#define IDIM   256
#define NU     512
#define NL     4
#define EU     2048
#define NH     8
#define DK     64
#define TT     1024
#define NB     8
#define MTOT   8192

typedef short  bf16x8 __attribute__((ext_vector_type(8)));
typedef float  f32x4  __attribute__((ext_vector_type(4)));
typedef unsigned short ushortv2 __attribute__((ext_vector_type(2)));

// fp32 -> bf16 bits, round-to-nearest-even
__device__ __forceinline__ unsigned short f2b(float x) {
  unsigned int u = __float_as_uint(x);
  u += 0x7fffu + ((u >> 16) & 1u);
  return (unsigned short)(u >> 16);
}

// ---------------------------------------------------------------------------
// fp32 -> bf16 bulk convert (8 elems/thread)
// ---------------------------------------------------------------------------
__global__ __launch_bounds__(256) void cvt_bf16(
    const float* __restrict__ src, unsigned short* __restrict__ dst, int n) {
  int i = (blockIdx.x * 256 + threadIdx.x) * 8;
  if (i >= n) return;
  float4 a = *(const float4*)(src + i);
  float4 b = *(const float4*)(src + i + 4);
  bf16x8 r;
  r[0] = (short)f2b(a.x); r[1] = (short)f2b(a.y);
  r[2] = (short)f2b(a.z); r[3] = (short)f2b(a.w);
  r[4] = (short)f2b(b.x); r[5] = (short)f2b(b.y);
  r[6] = (short)f2b(b.z); r[7] = (short)f2b(b.w);
  *(bf16x8*)(dst + i) = r;
}

// ---------------------------------------------------------------------------
// Round-7 proven GEMM core: BM=BN=128, BK=32, reg-staged with next-step
// register prefetch, LDS rows padded to 40 shorts (80B) -> 2-way-max bank
// aliasing on both ds_write and ds_read_b128 (free per m136).
// ---------------------------------------------------------------------------
#define GEMM_CORE(K_, KBEG, KEND)                                            \
  constexpr int LSTR = 40;                                                   \
  __shared__ unsigned short As[128 * LSTR];                                  \
  __shared__ unsigned short Bs[128 * LSTR];                                  \
  const int kdim = (K_);                                                     \
  const int tid  = threadIdx.x;                                              \
  const int lane = tid & 63;                                                 \
  const int wv   = tid >> 6;                                                 \
  const int wm   = (wv >> 1) * 64;                                           \
  const int wn   = (wv & 1) * 64;                                            \
  const int fr   = lane & 15;                                                \
  const int fc   = lane >> 4;                                                \
  const int sr   = tid >> 1;                                                 \
  const int sh   = (tid & 1) * 16;                                           \
  const short* aptr = (const short*)A + (size_t)(m0 + sr) * kdim + sh;       \
  const short* wptr = (const short*)W + (size_t)(n0 + sr) * kdim + sh;       \
  short* asd = (short*)&As[sr * LSTR + sh];                                  \
  short* bsd = (short*)&Bs[sr * LSTR + sh];                                  \
  f32x4 acc[4][4];                                                           \
  _Pragma("unroll") for (int i = 0; i < 4; ++i)                              \
    _Pragma("unroll") for (int j = 0; j < 4; ++j)                            \
      acc[i][j] = (f32x4){0.f, 0.f, 0.f, 0.f};                               \
  bf16x8 pa0 = *(const bf16x8*)(aptr + (KBEG));                              \
  bf16x8 pa1 = *(const bf16x8*)(aptr + (KBEG) + 8);                          \
  bf16x8 pb0 = *(const bf16x8*)(wptr + (KBEG));                              \
  bf16x8 pb1 = *(const bf16x8*)(wptr + (KBEG) + 8);                          \
  for (int k0 = (KBEG); k0 < (KEND); k0 += 32) {                             \
    __syncthreads();                                                         \
    *(bf16x8*)asd = pa0;  *(bf16x8*)(asd + 8) = pa1;                         \
    *(bf16x8*)bsd = pb0;  *(bf16x8*)(bsd + 8) = pb1;                         \
    __syncthreads();                                                         \
    const int kn = k0 + 32;                                                  \
    if (kn < (KEND)) {                                                       \
      pa0 = *(const bf16x8*)(aptr + kn);                                     \
      pa1 = *(const bf16x8*)(aptr + kn + 8);                                 \
      pb0 = *(const bf16x8*)(wptr + kn);                                     \
      pb1 = *(const bf16x8*)(wptr + kn + 8);                                 \
    }                                                                        \
    bf16x8 af[4], bfr[4];                                                    \
    _Pragma("unroll") for (int mi = 0; mi < 4; ++mi)                         \
      af[mi] = *(const bf16x8*)&As[(wm + mi * 16 + fr) * LSTR + fc * 8];     \
    _Pragma("unroll") for (int ni = 0; ni < 4; ++ni)                         \
      bfr[ni] = *(const bf16x8*)&Bs[(wn + ni * 16 + fr) * LSTR + fc * 8];    \
    _Pragma("unroll") for (int mi = 0; mi < 4; ++mi)                         \
      _Pragma("unroll") for (int ni = 0; ni < 4; ++ni)                       \
        acc[mi][ni] = __builtin_amdgcn_mfma_f32_16x16x32_bf16(               \
            af[mi], bfr[ni], acc[mi][ni], 0, 0, 0);                          \
  }

// 128x64-tile variant for the grid-starved N=512 GEMMs: 4 waves 2x2, each
// wave 64x32 (4x2 frags, 8 MFMA/step).  Grid doubles -> 4-6 blocks/CU.
#define GEMM_CORE64(K_, KBEG, KEND)                                          \
  constexpr int LSTR = 40;                                                   \
  __shared__ unsigned short As[128 * LSTR];                                  \
  __shared__ unsigned short Bs[64 * LSTR];                                   \
  const int kdim = (K_);                                                     \
  const int tid  = threadIdx.x;                                              \
  const int lane = tid & 63;                                                 \
  const int wv   = tid >> 6;                                                 \
  const int wm   = (wv >> 1) * 64;                                           \
  const int wn   = (wv & 1) * 32;                                            \
  const int fr   = lane & 15;                                                \
  const int fc   = lane >> 4;                                                \
  const int sr   = tid >> 1;                                                 \
  const int sh   = (tid & 1) * 16;                                           \
  const int sr2  = tid >> 2;                                                 \
  const int sh2  = (tid & 3) * 8;                                            \
  const short* aptr = (const short*)A + (size_t)(m0 + sr) * kdim + sh;       \
  const short* wptr = (const short*)W + (size_t)(n0 + sr2) * kdim + sh2;     \
  short* asd = (short*)&As[sr * LSTR + sh];                                  \
  short* bsd = (short*)&Bs[sr2 * LSTR + sh2];                                \
  f32x4 acc[4][2];                                                           \
  _Pragma("unroll") for (int i = 0; i < 4; ++i)                              \
    _Pragma("unroll") for (int j = 0; j < 2; ++j)                            \
      acc[i][j] = (f32x4){0.f, 0.f, 0.f, 0.f};                               \
  bf16x8 pa0 = *(const bf16x8*)(aptr + (KBEG));                              \
  bf16x8 pa1 = *(const bf16x8*)(aptr + (KBEG) + 8);                          \
  bf16x8 pb0 = *(const bf16x8*)(wptr + (KBEG));                              \
  for (int k0 = (KBEG); k0 < (KEND); k0 += 32) {                             \
    __syncthreads();                                                         \
    *(bf16x8*)asd = pa0;  *(bf16x8*)(asd + 8) = pa1;                         \
    *(bf16x8*)bsd = pb0;                                                     \
    __syncthreads();                                                         \
    const int kn = k0 + 32;                                                  \
    if (kn < (KEND)) {                                                       \
      pa0 = *(const bf16x8*)(aptr + kn);                                     \
      pa1 = *(const bf16x8*)(aptr + kn + 8);                                 \
      pb0 = *(const bf16x8*)(wptr + kn);                                     \
    }                                                                        \
    bf16x8 af[4], bfr[2];                                                    \
    _Pragma("unroll") for (int mi = 0; mi < 4; ++mi)                         \
      af[mi] = *(const bf16x8*)&As[(wm + mi * 16 + fr) * LSTR + fc * 8];     \
    _Pragma("unroll") for (int ni = 0; ni < 2; ++ni)                         \
      bfr[ni] = *(const bf16x8*)&Bs[(wn + ni * 16 + fr) * LSTR + fc * 8];    \
    _Pragma("unroll") for (int mi = 0; mi < 4; ++mi)                         \
      _Pragma("unroll") for (int ni = 0; ni < 2; ++ni)                       \
        acc[mi][ni] = __builtin_amdgcn_mfma_f32_16x16x32_bf16(               \
            af[mi], bfr[ni], acc[mi][ni], 0, 0, 0);                          \
  }

// MODE: 0 = fp32 store, 1 = bf16 store, 2 = fp32 atomicAdd (split-K).
template<int MODE, bool RELU>
__global__ __launch_bounds__(256) void gemm_bf(
    const unsigned short* __restrict__ A, const unsigned short* __restrict__ W,
    const float* __restrict__ bias, float* __restrict__ Cf,
    unsigned short* __restrict__ Cb, int M, int N, int K, int kchunk) {
  const int m0 = blockIdx.y * 128;
  const int n0 = blockIdx.x * 128;
  const int kbeg = blockIdx.z * kchunk;
  const int kend = kbeg + kchunk;
  GEMM_CORE(K, kbeg, kend)

  const bool addb = (blockIdx.z == 0);
#pragma unroll
  for (int ni = 0; ni < 4; ++ni) {
    const int col = n0 + wn + ni * 16 + fr;
    const float bb = (MODE != 2 || addb) ? bias[col] : 0.f;
#pragma unroll
    for (int mi = 0; mi < 4; ++mi) {
      const int row = m0 + wm + mi * 16 + fc * 4;
#pragma unroll
      for (int j = 0; j < 4; ++j) {
        size_t off = (size_t)(row + j) * N + col;
        float r = acc[mi][ni][j] + bb;
        if (RELU) r = fmaxf(r, 0.f);
        if (MODE == 0) Cf[off] = r;
        else if (MODE == 1) Cb[off] = f2b(r);
        else atomicAdd(&Cf[off], r);
      }
    }
  }
}

template<int MODE, bool RELU>
__global__ __launch_bounds__(256) void gemm_bf64(
    const unsigned short* __restrict__ A, const unsigned short* __restrict__ W,
    const float* __restrict__ bias, float* __restrict__ Cf,
    unsigned short* __restrict__ Cb, int M, int N, int K, int kchunk) {
  const int m0 = blockIdx.y * 128;
  const int n0 = blockIdx.x * 64;
  const int kbeg = blockIdx.z * kchunk;
  const int kend = kbeg + kchunk;
  GEMM_CORE64(K, kbeg, kend)

  const bool addb = (blockIdx.z == 0);
#pragma unroll
  for (int ni = 0; ni < 2; ++ni) {
    const int col = n0 + wn + ni * 16 + fr;
    const float bb = (MODE != 2 || addb) ? bias[col] : 0.f;
#pragma unroll
    for (int mi = 0; mi < 4; ++mi) {
      const int row = m0 + wm + mi * 16 + fc * 4;
#pragma unroll
      for (int j = 0; j < 4; ++j) {
        size_t off = (size_t)(row + j) * N + col;
        float r = acc[mi][ni][j] + bb;
        if (RELU) r = fmaxf(r, 0.f);
        if (MODE == 0) Cf[off] = r;
        else if (MODE == 1) Cb[off] = f2b(r);
        else atomicAdd(&Cf[off], r);
      }
    }
  }
}

// Fused QKV (128x64 tiles): blockIdx.z picks (W,bias,out); q scaled by 1/8.
__global__ __launch_bounds__(256) void gemm_qkv64(
    const unsigned short* __restrict__ A,
    const unsigned short* __restrict__ Wq, const unsigned short* __restrict__ Wk,
    const unsigned short* __restrict__ Wv,
    const float* __restrict__ bq, const float* __restrict__ bk,
    const float* __restrict__ bv,
    unsigned short* __restrict__ Oq, unsigned short* __restrict__ Ok,
    unsigned short* __restrict__ Ov) {
  const int zz = blockIdx.z;
  const unsigned short* W  = zz == 0 ? Wq : (zz == 1 ? Wk : Wv);
  const float* bias        = zz == 0 ? bq : (zz == 1 ? bk : bv);
  unsigned short* C        = zz == 0 ? Oq : (zz == 1 ? Ok : Ov);
  const float scale        = zz == 0 ? 0.125f : 1.0f;
  const int m0 = blockIdx.y * 128;
  const int n0 = blockIdx.x * 64;
  GEMM_CORE64(NU, 0, NU)

#pragma unroll
  for (int ni = 0; ni < 2; ++ni) {
    const int col = n0 + wn + ni * 16 + fr;
    const float bb = bias[col];
#pragma unroll
    for (int mi = 0; mi < 4; ++mi) {
      const int row = m0 + wm + mi * 16 + fc * 4;
#pragma unroll
      for (int j = 0; j < 4; ++j)
        C[(size_t)(row + j) * NU + col] = f2b((acc[mi][ni][j] + bb) * scale);
    }
  }
}

// ---------------------------------------------------------------------------
// In-place LayerNorm (fp32), optional bf16 copy for GEMM consumption.
// ---------------------------------------------------------------------------
template<bool WB>
__global__ __launch_bounds__(256) void layernorm_inplace(
    float* __restrict__ e, const float* __restrict__ g,
    const float* __restrict__ b, unsigned short* __restrict__ eb) {
  const int row = blockIdx.x;
  float* x = e + (size_t)row * NU;
  const int tid = threadIdx.x;

  float2 v = *(const float2*)&x[tid * 2];
  float sum = v.x + v.y;
  float sq  = v.x * v.x + v.y * v.y;
#pragma unroll
  for (int o = 32; o > 0; o >>= 1) {
    sum += __shfl_down(sum, o);
    sq  += __shfl_down(sq, o);
  }
  __shared__ float ps[4], pq[4], stat[2];
  const int wid = tid >> 6, lane = tid & 63;
  if (lane == 0) { ps[wid] = sum; pq[wid] = sq; }
  __syncthreads();
  if (tid == 0) {
    float s = ps[0] + ps[1] + ps[2] + ps[3];
    float q = pq[0] + pq[1] + pq[2] + pq[3];
    float mu = s * (1.0f / NU);
    float var = q * (1.0f / NU) - mu * mu;
    stat[0] = mu;
    stat[1] = rsqrtf(var + 1e-5f);
  }
  __syncthreads();
  const float mu = stat[0], rstd = stat[1];
  const float2 gg = *(const float2*)&g[tid * 2];
  const float2 bb = *(const float2*)&b[tid * 2];
  v.x = (v.x - mu) * rstd * gg.x + bb.x;
  v.y = (v.y - mu) * rstd * gg.y + bb.y;
  *(float2*)&x[tid * 2] = v;
  if (WB) {
    ushortv2 o = {f2b(v.x), f2b(v.y)};
    *(ushortv2*)&eb[(size_t)row * NU + tid * 2] = o;
  }
}

// ---------------------------------------------------------------------------
// MFMA flash attention (round-12 verified: Vt stride 66 + T13 defer-max).
// ---------------------------------------------------------------------------
__global__ __launch_bounds__(256) void flash_attn_mfma(
    const unsigned short* __restrict__ Q, const unsigned short* __restrict__ K,
    const unsigned short* __restrict__ V, unsigned short* __restrict__ O) {
  constexpr int LSTR = 72;
  constexpr int VSTR = 66;
  __shared__ unsigned short Ks[64 * LSTR];   // [k][d]
  __shared__ unsigned short Vt[64 * VSTR];   // [d][k]
  __shared__ unsigned short Ps[64 * LSTR];   // [q][k]

  const int b = blockIdx.z, h = blockIdx.y;
  const int q0 = blockIdx.x * 64;
  const int tid = threadIdx.x;
  const int lane = tid & 63;
  const int w = tid >> 6;
  const int fr = lane & 15;
  const int fc = lane >> 4;

  const size_t hb = ((size_t)b * TT) * NU + h * DK;

  bf16x8 qf[2];
#pragma unroll
  for (int kc = 0; kc < 2; ++kc)
    qf[kc] = *(const bf16x8*)(Q + hb +
        (size_t)(q0 + w * 16 + fr) * NU + kc * 32 + fc * 8);

  f32x4 ctx[4];
#pragma unroll
  for (int ni = 0; ni < 4; ++ni) ctx[ni] = (f32x4){0.f, 0.f, 0.f, 0.f};
  float m_run[4], l_run[4];
#pragma unroll
  for (int j = 0; j < 4; ++j) { m_run[j] = -1e30f; l_run[j] = 0.f; }

  const int sr = tid >> 2;
  const int sd = (tid & 3) * 16;

  for (int kt = 0; kt < TT; kt += 64) {
    const unsigned short* kp = K + hb + (size_t)(kt + sr) * NU + sd;
    const unsigned short* vp = V + hb + (size_t)(kt + sr) * NU + sd;
    bf16x8 k0 = *(const bf16x8*)kp, k1 = *(const bf16x8*)(kp + 8);
    bf16x8 v0 = *(const bf16x8*)vp, v1 = *(const bf16x8*)(vp + 8);

    __syncthreads();
    *(bf16x8*)&Ks[sr * LSTR + sd]     = k0;
    *(bf16x8*)&Ks[sr * LSTR + sd + 8] = k1;
#pragma unroll
    for (int t = 0; t < 8; ++t) {
      Vt[(sd + t)     * VSTR + sr] = (unsigned short)v0[t];
      Vt[(sd + t + 8) * VSTR + sr] = (unsigned short)v1[t];
    }
    __syncthreads();

    bf16x8 kf[4][2];
#pragma unroll
    for (int ni = 0; ni < 4; ++ni)
#pragma unroll
      for (int kc = 0; kc < 2; ++kc)
        kf[ni][kc] = *(const bf16x8*)&Ks[(ni * 16 + fr) * LSTR + kc * 32 + fc * 8];

    f32x4 sacc[4];
#pragma unroll
    for (int ni = 0; ni < 4; ++ni) sacc[ni] = (f32x4){0.f, 0.f, 0.f, 0.f};
#pragma unroll
    for (int kc = 0; kc < 2; ++kc)
#pragma unroll
      for (int ni = 0; ni < 4; ++ni)
        sacc[ni] = __builtin_amdgcn_mfma_f32_16x16x32_bf16(
            qf[kc], kf[ni][kc], sacc[ni], 0, 0, 0);

    float cm[4];
#pragma unroll
    for (int j = 0; j < 4; ++j)
      cm[j] = fmaxf(fmaxf(sacc[0][j], sacc[1][j]),
                    fmaxf(sacc[2][j], sacc[3][j]));
#pragma unroll
    for (int mask = 1; mask < 16; mask <<= 1)
#pragma unroll
      for (int j = 0; j < 4; ++j)
        cm[j] = fmaxf(cm[j], __shfl_xor(cm[j], mask));

    int need = (cm[0] > m_run[0] + 8.f) | (cm[1] > m_run[1] + 8.f) |
               (cm[2] > m_run[2] + 8.f) | (cm[3] > m_run[3] + 8.f);
    if (__any(need)) {
#pragma unroll
      for (int j = 0; j < 4; ++j) {
        float mn = fmaxf(m_run[j], cm[j]);
        float corr = __expf(m_run[j] - mn);
        m_run[j] = mn;
        l_run[j] *= corr;
#pragma unroll
        for (int ni = 0; ni < 4; ++ni) ctx[ni][j] *= corr;
      }
    }
#pragma unroll
    for (int j = 0; j < 4; ++j)
#pragma unroll
      for (int ni = 0; ni < 4; ++ni) {
        float p = __expf(sacc[ni][j] - m_run[j]);   // bounded by e^8
        l_run[j] += p;
        Ps[(w * 16 + fc * 4 + j) * LSTR + ni * 16 + fr] = f2b(p);
      }

    bf16x8 pf[2], vf[4][2];
#pragma unroll
    for (int kc = 0; kc < 2; ++kc)
      pf[kc] = *(const bf16x8*)&Ps[(w * 16 + fr) * LSTR + kc * 32 + fc * 8];
#pragma unroll
    for (int ni = 0; ni < 4; ++ni)
#pragma unroll
      for (int kc = 0; kc < 2; ++kc)
        vf[ni][kc] = *(const bf16x8*)&Vt[(ni * 16 + fr) * VSTR + kc * 32 + fc * 8];
#pragma unroll
    for (int kc = 0; kc < 2; ++kc)
#pragma unroll
      for (int ni = 0; ni < 4; ++ni)
        ctx[ni] = __builtin_amdgcn_mfma_f32_16x16x32_bf16(
            pf[kc], vf[ni][kc], ctx[ni], 0, 0, 0);
  }

#pragma unroll
  for (int j = 0; j < 4; ++j) {
    float l = l_run[j];
#pragma unroll
    for (int mask = 1; mask < 16; mask <<= 1)
      l += __shfl_xor(l, mask);
    const float inv = 1.0f / l;
    const int row = q0 + w * 16 + fc * 4 + j;
    unsigned short* dst = O + hb + (size_t)row * NU;
#pragma unroll
    for (int ni = 0; ni < 4; ++ni)
      dst[ni * 16 + fr] = f2b(ctx[ni][j] * inv);
  }
}

// ---------------------------------------------------------------------------
// Launcher.  ws (64MB) layout in bf16 units (1M = 1<<20 shorts):
//   [0,4M)q [4M,8M)k [8M,12M)v [12M,16M)ctx   --- hdn = [0,16M)
//   x_bf=[4M,6M) Win_bf=[6M,~) (dead before q/k/v written)
//   [16M,20M) e_bf
//   [20M,21M)Wq [21,22)Wk [22,23)Wv [23,24)Wo [24M,28M)W1 [28M,32M)W2
// ---------------------------------------------------------------------------
extern "C" void kernel_launch(void* const* d_in, const int* in_sizes, int n_in,
                              void* d_out, int out_size, void* d_ws, size_t ws_size,
                              hipStream_t stream) {
  const float* x     = (const float*)d_in[0];
  const float* Win   = (const float*)d_in[1];
  const float* bin_  = (const float*)d_in[2];
  const float* ln1_g = (const float*)d_in[3];
  const float* ln1_b = (const float*)d_in[4];
  const float* Wq    = (const float*)d_in[5];
  const float* bq    = (const float*)d_in[6];
  const float* Wk    = (const float*)d_in[7];
  const float* bk    = (const float*)d_in[8];
  const float* Wv    = (const float*)d_in[9];
  const float* bv    = (const float*)d_in[10];
  const float* Wo    = (const float*)d_in[11];
  const float* bo    = (const float*)d_in[12];
  const float* ln2_g = (const float*)d_in[13];
  const float* ln2_b = (const float*)d_in[14];
  const float* W1    = (const float*)d_in[15];
  const float* b1    = (const float*)d_in[16];
  const float* W2    = (const float*)d_in[17];
  const float* b2    = (const float*)d_in[18];
  const float* lno_g = (const float*)d_in[19];
  const float* lno_b = (const float*)d_in[20];

  float* e = (float*)d_out;
  unsigned short* wsb = (unsigned short*)d_ws;
  const size_t M1 = 1u << 20;
  unsigned short* q    = wsb;
  unsigned short* k    = wsb + 4 * M1;
  unsigned short* v    = wsb + 8 * M1;
  unsigned short* ctx  = wsb + 12 * M1;
  unsigned short* hdn  = wsb;                 // [0,16M)
  unsigned short* xbf  = wsb + 4 * M1;        // dead before k written
  unsigned short* winb = wsb + 6 * M1;
  unsigned short* ebf  = wsb + 16 * M1;
  unsigned short* wqb  = wsb + 20 * M1;
  unsigned short* wkb  = wsb + 21 * M1;
  unsigned short* wvb  = wsb + 22 * M1;
  unsigned short* wob  = wsb + 23 * M1;
  unsigned short* w1b  = wsb + 24 * M1;
  unsigned short* w2b  = wsb + 28 * M1;

  const dim3 blk(256);
  cvt_bf16<<<1024, blk, 0, stream>>>(x,   xbf,  MTOT * IDIM);
  cvt_bf16<<<64,   blk, 0, stream>>>(Win, winb, NU * IDIM);
  cvt_bf16<<<512,  blk, 0, stream>>>(Wq,  wqb,  NL * NU * NU);
  cvt_bf16<<<512,  blk, 0, stream>>>(Wk,  wkb,  NL * NU * NU);
  cvt_bf16<<<512,  blk, 0, stream>>>(Wv,  wvb,  NL * NU * NU);
  cvt_bf16<<<512,  blk, 0, stream>>>(Wo,  wob,  NL * NU * NU);
  cvt_bf16<<<2048, blk, 0, stream>>>(W1,  w1b,  NL * EU * NU);
  cvt_bf16<<<2048, blk, 0, stream>>>(W2,  w2b,  NL * NU * EU);

  const dim3 gProjIn(NU / 64, MTOT / 128);       // (8,64)   512 blocks
  const dim3 gQKV(NU / 64, MTOT / 128, 3);       // (8,64,3) 1536 blocks
  const dim3 gWo(NU / 64, MTOT / 128, 2);        // (8,64,2) 1024, split-K 2
  const dim3 gF1(EU / 128, MTOT / 128);          // (16,64)  1024 (control, 128^2)
  const dim3 gF2(NU / 64, MTOT / 128, 2);        // (8,64,2) 1024, split-K 2
  const dim3 gAttn(TT / 64, NH, NB);             // 1024

  // e = x @ Win^T + bin   (fp32 out)
  gemm_bf64<0, false><<<gProjIn, blk, 0, stream>>>(
      xbf, winb, bin_, e, nullptr, MTOT, NU, IDIM, IDIM);

  for (int i = 0; i < NL; ++i) {
    layernorm_inplace<true><<<MTOT, blk, 0, stream>>>(e, ln1_g + i * NU, ln1_b + i * NU, ebf);

    gemm_qkv64<<<gQKV, blk, 0, stream>>>(ebf, wqb + (size_t)i * NU * NU,
                                         wkb + (size_t)i * NU * NU,
                                         wvb + (size_t)i * NU * NU,
                                         bq + i * NU, bk + i * NU, bv + i * NU,
                                         q, k, v);

    flash_attn_mfma<<<gAttn, blk, 0, stream>>>(q, k, v, ctx);

    // e += ctx @ Wo^T + bo   (split-K 2, atomic)
    gemm_bf64<2, false><<<gWo, blk, 0, stream>>>(
        ctx, wob + (size_t)i * NU * NU, bo + i * NU, e, nullptr,
        MTOT, NU, NU, NU / 2);

    layernorm_inplace<true><<<MTOT, blk, 0, stream>>>(e, ln2_g + i * NU, ln2_b + i * NU, ebf);

    // hdn = relu(ebf @ W1^T + b1)  (bf16 out; 128^2 control kernel)
    gemm_bf<1, true><<<gF1, blk, 0, stream>>>(
        ebf, w1b + (size_t)i * EU * NU, b1 + i * EU, nullptr, hdn,
        MTOT, EU, NU, NU);

    // e += hdn @ W2^T + b2   (split-K 2, atomic)
    gemm_bf64<2, false><<<gF2, blk, 0, stream>>>(
        hdn, w2b + (size_t)i * NU * EU, b2 + i * NU, e, nullptr,
        MTOT, NU, EU, EU / 2);
  }

  layernorm_inplace<false><<<MTOT, blk, 0, stream>>>(e, lno_g, lno_b, nullptr);
}

// Round 14
// 982.642 us; speedup vs baseline: 1.2330x; 1.1300x over previous
//
#include <hip/hip_runtime.h>
#include <hip/hip_bf16.h>
#include <math.h>
#include <stdint.h>

#define IDIM   256
#define NU     512
#define NL     4
#define EU     2048
#define NH     8
#define DK     64
#define TT     1024
#define NB     8
#define MTOT   8192

typedef short  bf16x8 __attribute__((ext_vector_type(8)));
typedef float  f32x4  __attribute__((ext_vector_type(4)));
typedef unsigned short ushort4v __attribute__((ext_vector_type(4)));
typedef unsigned short ushort8v __attribute__((ext_vector_type(8)));

// fp32 -> bf16 bits, round-to-nearest-even
__device__ __forceinline__ unsigned short f2b(float x) {
  unsigned int u = __float_as_uint(x);
  u += 0x7fffu + ((u >> 16) & 1u);
  return (unsigned short)(u >> 16);
}

// ---------------------------------------------------------------------------
// Merged one-dispatch fp32->bf16 convert.  Segment table (blocks of 2048
// elems): x 1024 | Win 64 | Wq 512 | Wk 512 | Wv 512 | Wo 512 | W1 2048 | W2 2048
// ---------------------------------------------------------------------------
__device__ __forceinline__ void cvt_seg(const float* s, unsigned short* d, int blk) {
  int i = (blk * 256 + (int)threadIdx.x) * 8;
  float4 a = *(const float4*)(s + i);
  float4 b = *(const float4*)(s + i + 4);
  ushort8v r = {f2b(a.x), f2b(a.y), f2b(a.z), f2b(a.w),
                f2b(b.x), f2b(b.y), f2b(b.z), f2b(b.w)};
  *(ushort8v*)(d + i) = r;
}

__global__ __launch_bounds__(256) void cvt_all(
    const float* x, const float* Win, const float* Wq, const float* Wk,
    const float* Wv, const float* Wo, const float* W1, const float* W2,
    unsigned short* xb, unsigned short* winb, unsigned short* wqb,
    unsigned short* wkb, unsigned short* wvb, unsigned short* wob,
    unsigned short* w1b, unsigned short* w2b) {
  int b = blockIdx.x;
  if      (b < 1024) cvt_seg(x,   xb,   b);
  else if (b < 1088) cvt_seg(Win, winb, b - 1024);
  else if (b < 1600) cvt_seg(Wq,  wqb,  b - 1088);
  else if (b < 2112) cvt_seg(Wk,  wkb,  b - 1600);
  else if (b < 2624) cvt_seg(Wv,  wvb,  b - 2112);
  else if (b < 3136) cvt_seg(Wo,  wob,  b - 2624);
  else if (b < 5184) cvt_seg(W1,  w1b,  b - 3136);
  else               cvt_seg(W2,  w2b,  b - 5184);
}

// ---------------------------------------------------------------------------
// Round-7 proven GEMM core: BM=BN=128, BK=32, reg-staged + next-step register
// prefetch, LDS rows padded to 40 shorts (80B) -> 2-way-max bank aliasing.
// ---------------------------------------------------------------------------
#define GEMM_CORE(K_, KBEG, KEND)                                            \
  constexpr int LSTR = 40;                                                   \
  __shared__ unsigned short As[128 * LSTR];                                  \
  __shared__ unsigned short Bs[128 * LSTR];                                  \
  const int kdim = (K_);                                                     \
  const int tid  = threadIdx.x;                                              \
  const int lane = tid & 63;                                                 \
  const int wv   = tid >> 6;                                                 \
  const int wm   = (wv >> 1) * 64;                                           \
  const int wn   = (wv & 1) * 64;                                            \
  const int fr   = lane & 15;                                                \
  const int fc   = lane >> 4;                                                \
  const int sr   = tid >> 1;                                                 \
  const int sh   = (tid & 1) * 16;                                           \
  const short* aptr = (const short*)A + (size_t)(m0 + sr) * kdim + sh;       \
  const short* wptr = (const short*)W + (size_t)(n0 + sr) * kdim + sh;       \
  short* asd = (short*)&As[sr * LSTR + sh];                                  \
  short* bsd = (short*)&Bs[sr * LSTR + sh];                                  \
  f32x4 acc[4][4];                                                           \
  _Pragma("unroll") for (int i = 0; i < 4; ++i)                              \
    _Pragma("unroll") for (int j = 0; j < 4; ++j)                            \
      acc[i][j] = (f32x4){0.f, 0.f, 0.f, 0.f};                               \
  bf16x8 pa0 = *(const bf16x8*)(aptr + (KBEG));                              \
  bf16x8 pa1 = *(const bf16x8*)(aptr + (KBEG) + 8);                          \
  bf16x8 pb0 = *(const bf16x8*)(wptr + (KBEG));                              \
  bf16x8 pb1 = *(const bf16x8*)(wptr + (KBEG) + 8);                          \
  for (int k0 = (KBEG); k0 < (KEND); k0 += 32) {                             \
    __syncthreads();                                                         \
    *(bf16x8*)asd = pa0;  *(bf16x8*)(asd + 8) = pa1;                         \
    *(bf16x8*)bsd = pb0;  *(bf16x8*)(bsd + 8) = pb1;                         \
    __syncthreads();                                                         \
    const int kn = k0 + 32;                                                  \
    if (kn < (KEND)) {                                                       \
      pa0 = *(const bf16x8*)(aptr + kn);                                     \
      pa1 = *(const bf16x8*)(aptr + kn + 8);                                 \
      pb0 = *(const bf16x8*)(wptr + kn);                                     \
      pb1 = *(const bf16x8*)(wptr + kn + 8);                                 \
    }                                                                        \
    bf16x8 af[4], bfr[4];                                                    \
    _Pragma("unroll") for (int mi = 0; mi < 4; ++mi)                         \
      af[mi] = *(const bf16x8*)&As[(wm + mi * 16 + fr) * LSTR + fc * 8];     \
    _Pragma("unroll") for (int ni = 0; ni < 4; ++ni)                         \
      bfr[ni] = *(const bf16x8*)&Bs[(wn + ni * 16 + fr) * LSTR + fc * 8];    \
    _Pragma("unroll") for (int mi = 0; mi < 4; ++mi)                         \
      _Pragma("unroll") for (int ni = 0; ni < 4; ++ni)                       \
        acc[mi][ni] = __builtin_amdgcn_mfma_f32_16x16x32_bf16(               \
            af[mi], bfr[ni], acc[mi][ni], 0, 0, 0);                          \
  }

// MODE: 0 = fp32 store, 1 = bf16 store, 2 = fp32 atomicAdd (split-K).
template<int MODE, bool RELU>
__global__ __launch_bounds__(256) void gemm_bf(
    const unsigned short* __restrict__ A, const unsigned short* __restrict__ W,
    const float* __restrict__ bias, float* __restrict__ Cf,
    unsigned short* __restrict__ Cb, int M, int N, int K, int kchunk) {
  const int m0 = blockIdx.y * 128;
  const int n0 = blockIdx.x * 128;
  const int kbeg = blockIdx.z * kchunk;
  const int kend = kbeg + kchunk;
  GEMM_CORE(K, kbeg, kend)

  const bool addb = (blockIdx.z == 0);
#pragma unroll
  for (int ni = 0; ni < 4; ++ni) {
    const int col = n0 + wn + ni * 16 + fr;
    const float bb = (MODE != 2 || addb) ? bias[col] : 0.f;
#pragma unroll
    for (int mi = 0; mi < 4; ++mi) {
      const int row = m0 + wm + mi * 16 + fc * 4;
#pragma unroll
      for (int j = 0; j < 4; ++j) {
        size_t off = (size_t)(row + j) * N + col;
        float r = acc[mi][ni][j] + bb;
        if (RELU) r = fmaxf(r, 0.f);
        if (MODE == 0) Cf[off] = r;
        else if (MODE == 1) Cb[off] = f2b(r);
        else atomicAdd(&Cf[off], r);
      }
    }
  }
}

// Fused QKV: blockIdx.z picks (W,bias,out).  q scaled by 1/8 (exact).
// V (zz==2) is stored TRANSPOSED per head: vT[((b*NH+h)*DK+d)*TT + t],
// so attention can stage V^T tiles with vectorized b128 (no in-kernel
// transpose).  t runs j=0..3 consecutive -> ushort4 (8B aligned) stores.
__global__ __launch_bounds__(256) void gemm_qkv(
    const unsigned short* __restrict__ A,
    const unsigned short* __restrict__ Wq, const unsigned short* __restrict__ Wk,
    const unsigned short* __restrict__ Wv,
    const float* __restrict__ bq, const float* __restrict__ bk,
    const float* __restrict__ bv,
    unsigned short* __restrict__ Oq, unsigned short* __restrict__ Ok,
    unsigned short* __restrict__ Ovt) {
  const int zz = blockIdx.z;
  const unsigned short* W  = zz == 0 ? Wq : (zz == 1 ? Wk : Wv);
  const float* bias        = zz == 0 ? bq : (zz == 1 ? bk : bv);
  const float scale        = zz == 0 ? 0.125f : 1.0f;
  const int m0 = blockIdx.y * 128;
  const int n0 = blockIdx.x * 128;
  GEMM_CORE(NU, 0, NU)

  if (zz < 2) {
    unsigned short* C = zz == 0 ? Oq : Ok;
#pragma unroll
    for (int ni = 0; ni < 4; ++ni) {
      const int col = n0 + wn + ni * 16 + fr;
      const float bb = bias[col];
#pragma unroll
      for (int mi = 0; mi < 4; ++mi) {
        const int row = m0 + wm + mi * 16 + fc * 4;
#pragma unroll
        for (int j = 0; j < 4; ++j)
          C[(size_t)(row + j) * NU + col] = f2b((acc[mi][ni][j] + bb) * scale);
      }
    }
  } else {
    // transposed V store (tile never crosses a batch boundary: 1024%128==0)
#pragma unroll
    for (int ni = 0; ni < 4; ++ni) {
      const int col = n0 + wn + ni * 16 + fr;     // h*64 + d
      const float bb = bias[col];
      const int h = col >> 6, d = col & 63;
#pragma unroll
      for (int mi = 0; mi < 4; ++mi) {
        const int row = m0 + wm + mi * 16 + fc * 4;
        const int bi = row >> 10, t = row & 1023;
        ushort4v o = {f2b(acc[mi][ni][0] + bb), f2b(acc[mi][ni][1] + bb),
                      f2b(acc[mi][ni][2] + bb), f2b(acc[mi][ni][3] + bb)};
        *(ushort4v*)&Ovt[(size_t)(((bi * NH + h) * DK) + d) * TT + t] = o;
      }
    }
  }
}

// ---------------------------------------------------------------------------
// Wave-per-row LayerNorm: 4 rows/block (one 64-lane wave each), no LDS,
// no barriers.  8 floats/lane, full-wave shfl_xor butterfly.
// ---------------------------------------------------------------------------
template<bool WB>
__global__ __launch_bounds__(256) void layernorm_wave(
    float* __restrict__ e, const float* __restrict__ g,
    const float* __restrict__ b, unsigned short* __restrict__ eb) {
  const int lane = threadIdx.x & 63;
  const int row = blockIdx.x * 4 + (threadIdx.x >> 6);
  float* x = e + (size_t)row * NU + lane * 8;

  float4 v0 = *(const float4*)x;
  float4 v1 = *(const float4*)(x + 4);
  float sum = v0.x + v0.y + v0.z + v0.w + v1.x + v1.y + v1.z + v1.w;
  float sq  = v0.x*v0.x + v0.y*v0.y + v0.z*v0.z + v0.w*v0.w +
              v1.x*v1.x + v1.y*v1.y + v1.z*v1.z + v1.w*v1.w;
#pragma unroll
  for (int o = 32; o > 0; o >>= 1) {
    sum += __shfl_xor(sum, o);
    sq  += __shfl_xor(sq, o);
  }
  const float mu = sum * (1.0f / NU);
  const float rstd = rsqrtf(sq * (1.0f / NU) - mu * mu + 1e-5f);

  const float4 g0 = *(const float4*)&g[lane * 8];
  const float4 g1 = *(const float4*)&g[lane * 8 + 4];
  const float4 b0 = *(const float4*)&b[lane * 8];
  const float4 b1 = *(const float4*)&b[lane * 8 + 4];
  v0.x = (v0.x - mu) * rstd * g0.x + b0.x;
  v0.y = (v0.y - mu) * rstd * g0.y + b0.y;
  v0.z = (v0.z - mu) * rstd * g0.z + b0.z;
  v0.w = (v0.w - mu) * rstd * g0.w + b0.w;
  v1.x = (v1.x - mu) * rstd * g1.x + b1.x;
  v1.y = (v1.y - mu) * rstd * g1.y + b1.y;
  v1.z = (v1.z - mu) * rstd * g1.z + b1.z;
  v1.w = (v1.w - mu) * rstd * g1.w + b1.w;
  *(float4*)x = v0;
  *(float4*)(x + 4) = v1;
  if (WB) {
    ushort8v o = {f2b(v0.x), f2b(v0.y), f2b(v0.z), f2b(v0.w),
                  f2b(v1.x), f2b(v1.y), f2b(v1.z), f2b(v1.w)};
    *(ushort8v*)&eb[(size_t)row * NU + lane * 8] = o;
  }
}

// ---------------------------------------------------------------------------
// MFMA flash attention.  V arrives PRE-TRANSPOSED (vT[(b,h,d),t]) so both
// Ks and Vt stage with identical vectorized b128 writes (no scalar LDS).
// T13 defer-max retained.  Ps transpose-write remains scalar (C->A layout).
// ---------------------------------------------------------------------------
__global__ __launch_bounds__(256) void flash_attn_mfma(
    const unsigned short* __restrict__ Q, const unsigned short* __restrict__ K,
    const unsigned short* __restrict__ VT, unsigned short* __restrict__ O) {
  constexpr int LSTR = 72;
  __shared__ unsigned short Ks[64 * LSTR];   // [k][d]
  __shared__ unsigned short Vt[64 * LSTR];   // [d][k]
  __shared__ unsigned short Ps[64 * LSTR];   // [q][k]

  const int b = blockIdx.z, h = blockIdx.y;
  const int q0 = blockIdx.x * 64;
  const int tid = threadIdx.x;
  const int lane = tid & 63;
  const int w = tid >> 6;
  const int fr = lane & 15;
  const int fc = lane >> 4;

  const size_t hb = ((size_t)b * TT) * NU + h * DK;
  const size_t vb = ((size_t)(b * NH + h)) * DK * TT;

  bf16x8 qf[2];
#pragma unroll
  for (int kc = 0; kc < 2; ++kc)
    qf[kc] = *(const bf16x8*)(Q + hb +
        (size_t)(q0 + w * 16 + fr) * NU + kc * 32 + fc * 8);

  f32x4 ctx[4];
#pragma unroll
  for (int ni = 0; ni < 4; ++ni) ctx[ni] = (f32x4){0.f, 0.f, 0.f, 0.f};
  float m_run[4], l_run[4];
#pragma unroll
  for (int j = 0; j < 4; ++j) { m_run[j] = -1e30f; l_run[j] = 0.f; }

  const int sr = tid >> 2;            // K: key row / V: d row
  const int sd = (tid & 3) * 16;      // 16-elem chunk

  for (int kt = 0; kt < TT; kt += 64) {
    const unsigned short* kp = K + hb + (size_t)(kt + sr) * NU + sd;
    const unsigned short* vp = VT + vb + (size_t)sr * TT + kt + sd;
    bf16x8 k0 = *(const bf16x8*)kp, k1 = *(const bf16x8*)(kp + 8);
    bf16x8 v0 = *(const bf16x8*)vp, v1 = *(const bf16x8*)(vp + 8);

    __syncthreads();
    *(bf16x8*)&Ks[sr * LSTR + sd]     = k0;
    *(bf16x8*)&Ks[sr * LSTR + sd + 8] = k1;
    *(bf16x8*)&Vt[sr * LSTR + sd]     = v0;
    *(bf16x8*)&Vt[sr * LSTR + sd + 8] = v1;
    __syncthreads();

    bf16x8 kf[4][2];
#pragma unroll
    for (int ni = 0; ni < 4; ++ni)
#pragma unroll
      for (int kc = 0; kc < 2; ++kc)
        kf[ni][kc] = *(const bf16x8*)&Ks[(ni * 16 + fr) * LSTR + kc * 32 + fc * 8];

    f32x4 sacc[4];
#pragma unroll
    for (int ni = 0; ni < 4; ++ni) sacc[ni] = (f32x4){0.f, 0.f, 0.f, 0.f};
#pragma unroll
    for (int kc = 0; kc < 2; ++kc)
#pragma unroll
      for (int ni = 0; ni < 4; ++ni)
        sacc[ni] = __builtin_amdgcn_mfma_f32_16x16x32_bf16(
            qf[kc], kf[ni][kc], sacc[ni], 0, 0, 0);

    float cm[4];
#pragma unroll
    for (int j = 0; j < 4; ++j)
      cm[j] = fmaxf(fmaxf(sacc[0][j], sacc[1][j]),
                    fmaxf(sacc[2][j], sacc[3][j]));
#pragma unroll
    for (int mask = 1; mask < 16; mask <<= 1)
#pragma unroll
      for (int j = 0; j < 4; ++j)
        cm[j] = fmaxf(cm[j], __shfl_xor(cm[j], mask));

    int need = (cm[0] > m_run[0] + 8.f) | (cm[1] > m_run[1] + 8.f) |
               (cm[2] > m_run[2] + 8.f) | (cm[3] > m_run[3] + 8.f);
    if (__any(need)) {
#pragma unroll
      for (int j = 0; j < 4; ++j) {
        float mn = fmaxf(m_run[j], cm[j]);
        float corr = __expf(m_run[j] - mn);
        m_run[j] = mn;
        l_run[j] *= corr;
#pragma unroll
        for (int ni = 0; ni < 4; ++ni) ctx[ni][j] *= corr;
      }
    }
#pragma unroll
    for (int j = 0; j < 4; ++j)
#pragma unroll
      for (int ni = 0; ni < 4; ++ni) {
        float p = __expf(sacc[ni][j] - m_run[j]);   // bounded by e^8
        l_run[j] += p;
        Ps[(w * 16 + fc * 4 + j) * LSTR + ni * 16 + fr] = f2b(p);
      }

    bf16x8 pf[2], vf[4][2];
#pragma unroll
    for (int kc = 0; kc < 2; ++kc)
      pf[kc] = *(const bf16x8*)&Ps[(w * 16 + fr) * LSTR + kc * 32 + fc * 8];
#pragma unroll
    for (int ni = 0; ni < 4; ++ni)
#pragma unroll
      for (int kc = 0; kc < 2; ++kc)
        vf[ni][kc] = *(const bf16x8*)&Vt[(ni * 16 + fr) * LSTR + kc * 32 + fc * 8];
#pragma unroll
    for (int kc = 0; kc < 2; ++kc)
#pragma unroll
      for (int ni = 0; ni < 4; ++ni)
        ctx[ni] = __builtin_amdgcn_mfma_f32_16x16x32_bf16(
            pf[kc], vf[ni][kc], ctx[ni], 0, 0, 0);
  }

#pragma unroll
  for (int j = 0; j < 4; ++j) {
    float l = l_run[j];
#pragma unroll
    for (int mask = 1; mask < 16; mask <<= 1)
      l += __shfl_xor(l, mask);
    const float inv = 1.0f / l;
    const int row = q0 + w * 16 + fc * 4 + j;
    unsigned short* dst = O + hb + (size_t)row * NU;
#pragma unroll
    for (int ni = 0; ni < 4; ++ni)
      dst[ni * 16 + fr] = f2b(ctx[ni][j] * inv);
  }
}

// ---------------------------------------------------------------------------
// Launcher.  ws (64MB) layout in bf16 units (1M = 1<<20 shorts):
//   [0,4M)q [4M,8M)k [8M,12M)vT [12M,16M)ctx   --- hdn = [0,16M)
//   x_bf=[4M,6M) Win_bf=[6M,~) (dead before q/k written)
//   [16M,20M) e_bf
//   [20M,21M)Wq [21,22)Wk [22,23)Wv [23,24)Wo [24M,28M)W1 [28M,32M)W2
// ---------------------------------------------------------------------------
extern "C" void kernel_launch(void* const* d_in, const int* in_sizes, int n_in,
                              void* d_out, int out_size, void* d_ws, size_t ws_size,
                              hipStream_t stream) {
  const float* x     = (const float*)d_in[0];
  const float* Win   = (const float*)d_in[1];
  const float* bin_  = (const float*)d_in[2];
  const float* ln1_g = (const float*)d_in[3];
  const float* ln1_b = (const float*)d_in[4];
  const float* Wq    = (const float*)d_in[5];
  const float* bq    = (const float*)d_in[6];
  const float* Wk    = (const float*)d_in[7];
  const float* bk    = (const float*)d_in[8];
  const float* Wv    = (const float*)d_in[9];
  const float* bv    = (const float*)d_in[10];
  const float* Wo    = (const float*)d_in[11];
  const float* bo    = (const float*)d_in[12];
  const float* ln2_g = (const float*)d_in[13];
  const float* ln2_b = (const float*)d_in[14];
  const float* W1    = (const float*)d_in[15];
  const float* b1    = (const float*)d_in[16];
  const float* W2    = (const float*)d_in[17];
  const float* b2    = (const float*)d_in[18];
  const float* lno_g = (const float*)d_in[19];
  const float* lno_b = (const float*)d_in[20];

  float* e = (float*)d_out;
  unsigned short* wsb = (unsigned short*)d_ws;
  const size_t M1 = 1u << 20;
  unsigned short* q    = wsb;
  unsigned short* k    = wsb + 4 * M1;
  unsigned short* vT   = wsb + 8 * M1;
  unsigned short* ctx  = wsb + 12 * M1;
  unsigned short* hdn  = wsb;                 // [0,16M)
  unsigned short* xbf  = wsb + 4 * M1;        // dead before k written
  unsigned short* winb = wsb + 6 * M1;
  unsigned short* ebf  = wsb + 16 * M1;
  unsigned short* wqb  = wsb + 20 * M1;
  unsigned short* wkb  = wsb + 21 * M1;
  unsigned short* wvb  = wsb + 22 * M1;
  unsigned short* wob  = wsb + 23 * M1;
  unsigned short* w1b  = wsb + 24 * M1;
  unsigned short* w2b  = wsb + 28 * M1;

  const dim3 blk(256);
  cvt_all<<<7232, blk, 0, stream>>>(x, Win, Wq, Wk, Wv, Wo, W1, W2,
                                    xbf, winb, wqb, wkb, wvb, wob, w1b, w2b);

  const dim3 gProjIn(NU / 128, MTOT / 128);      // 256 blocks
  const dim3 gQKV(NU / 128, MTOT / 128, 3);      // 768
  const dim3 gWo(NU / 128, MTOT / 128, 2);       // 512, split-K 2
  const dim3 gF1(EU / 128, MTOT / 128);          // 1024
  const dim3 gF2(NU / 128, MTOT / 128, 2);       // 512, split-K 2
  const dim3 gAttn(TT / 64, NH, NB);             // 1024
  const dim3 gLN(MTOT / 4);                      // 2048

  // e = x @ Win^T + bin   (fp32 out)
  gemm_bf<0, false><<<gProjIn, blk, 0, stream>>>(
      xbf, winb, bin_, e, nullptr, MTOT, NU, IDIM, IDIM);

  for (int i = 0; i < NL; ++i) {
    layernorm_wave<true><<<gLN, blk, 0, stream>>>(e, ln1_g + i * NU, ln1_b + i * NU, ebf);

    gemm_qkv<<<gQKV, blk, 0, stream>>>(ebf, wqb + (size_t)i * NU * NU,
                                       wkb + (size_t)i * NU * NU,
                                       wvb + (size_t)i * NU * NU,
                                       bq + i * NU, bk + i * NU, bv + i * NU,
                                       q, k, vT);

    flash_attn_mfma<<<gAttn, blk, 0, stream>>>(q, k, vT, ctx);

    // e += ctx @ Wo^T + bo   (split-K 2, atomic)
    gemm_bf<2, false><<<gWo, blk, 0, stream>>>(
        ctx, wob + (size_t)i * NU * NU, bo + i * NU, e, nullptr,
        MTOT, NU, NU, NU / 2);

    layernorm_wave<true><<<gLN, blk, 0, stream>>>(e, ln2_g + i * NU, ln2_b + i * NU, ebf);

    // hdn = relu(ebf @ W1^T + b1)  (bf16 out)
    gemm_bf<1, true><<<gF1, blk, 0, stream>>>(
        ebf, w1b + (size_t)i * EU * NU, b1 + i * EU, nullptr, hdn,
        MTOT, EU, NU, NU);

    // e += hdn @ W2^T + b2   (split-K 2, atomic)
    gemm_bf<2, false><<<gF2, blk, 0, stream>>>(
        hdn, w2b + (size_t)i * NU * EU, b2 + i * NU, e, nullptr,
        MTOT, NU, EU, EU / 2);
  }

  layernorm_wave<false><<<gLN, blk, 0, stream>>>(e, lno_g, lno_b, nullptr);
}